// Round 3
// baseline (306.068 us; speedup 1.0000x reference)
//
#include <hip/hip_runtime.h>
#include <cstdint>
#include <cmath>

// Problem constants (fixed by setup_inputs)
#define NROWS 32768
#define HD    1024
#define NMOT  128
#define NCLS  16
#define KSEL  32
#define EPSV  1e-4f

typedef __attribute__((ext_vector_type(4))) float  f32x4;
typedef __attribute__((ext_vector_type(8))) __bf16 bf16x8;
typedef __attribute__((ext_vector_type(4))) __bf16 bf16x4;

// ---- workspace layout (in floats) ----
// wsf[0]              : loss accumulator
// wsf[64..191]        : motif squared norms mn[128]
// wsf[256..65792)     : mvbf — mv converted to bf16 (128x1024)
// wsf[65792..327936)  : cd[32768][8] — per-row distances to its 8 same-class motifs
// wsf[327936..360704) : s1v[1024][32] — stage-1 top-32 values
// wsf[360704..393472) : s1i[1024][32] — stage-1 top-32 indices (as int)
#define WS_MN   64
#define WS_MVBF 256
#define WS_CD   65792
#define WS_S1V  327936
#define WS_S1I  360704

static __device__ __forceinline__ float dot4(float4 v) {
    return v.x * v.x + v.y * v.y + v.z * v.z + v.w * v.w;
}

static __device__ __forceinline__ bf16x4 cvt4(float4 v) {
    bf16x4 t;
    t[0] = (__bf16)v.x; t[1] = (__bf16)v.y; t[2] = (__bf16)v.z; t[3] = (__bf16)v.w;
    return t;
}

// ---------------------------------------------------------------------------
// Kernel 1: motif norms + bf16 copy of mv + zero the loss accumulator
// ---------------------------------------------------------------------------
__global__ __launch_bounds__(256) void prep_k(const float* __restrict__ mv,
                                              float* __restrict__ wsf,
                                              __bf16* __restrict__ mvbf) {
    const int j = blockIdx.x;
    const int k = threadIdx.x * 4;           // 256 threads x 4 = 1024 = HD
    float4 v = *(const float4*)&mv[(size_t)j * HD + k];
    *(bf16x4*)&mvbf[(size_t)j * HD + k] = cvt4(v);
    float s = dot4(v);
#pragma unroll
    for (int o = 1; o < 64; o <<= 1) s += __shfl_xor(s, o, 64);
    __shared__ float red[4];
    if ((threadIdx.x & 63) == 0) red[threadIdx.x >> 6] = s;
    __syncthreads();
    if (threadIdx.x == 0) {
        wsf[WS_MN + j] = red[0] + red[1] + red[2] + red[3];
        if (j == 0) wsf[0] = 0.f;
    }
}

// ---------------------------------------------------------------------------
// Kernel 2: bf16-MFMA GEMM (z @ M^T) fused with ||z||^2, distance epilogue,
// full contrastive loss, and compact same-class distance write cd[N][8].
// Tile: 128 rows x 128 cols (all motifs), BK=32, 256 blocks, 256 threads.
// 4 waves in a 2x2 grid; each wave computes 64x64 = 4x4 MFMAs of 16x16x32.
// ---------------------------------------------------------------------------
#define BM 128
#define BN 128
#define BK 32
#define SA 40   // padded LDS stride in bf16 elems (80B)

__global__ __launch_bounds__(256, 3) void gemm_fused(
    const float* __restrict__ z, const __bf16* __restrict__ mvbf,
    const float* __restrict__ mn, float* __restrict__ cd,
    const int* __restrict__ y, float* __restrict__ lossAcc) {
    __shared__ __bf16 As[BM * SA];
    __shared__ __bf16 Bs[BN * SA];
    __shared__ float  szn[BM];
    __shared__ int    ly[BM];
    __shared__ float  spm[2][BM];
    __shared__ float  sns[2][BM];

    const int tid  = threadIdx.x;
    const int row0 = blockIdx.x * BM;
    const int lane = tid & 63;
    const int wave = tid >> 6;
    const int wr   = wave >> 1;   // 0..1 : 64-row strip
    const int wc   = wave & 1;    // 0..1 : 64-col strip
    const int l15  = lane & 15;
    const int quad = lane >> 4;

    const int sq = tid & 7;       // A staging: float4 slot in 32-wide k slab
    const int sr = tid >> 3;      // A staging: base row 0..31 (4 rows, +32 apart)
    const int bq = tid & 3;       // B staging: 16B chunk in k-slab
    const int br = tid >> 2;      // B staging: base row 0..63 (2 rows, +64 apart)

    if (tid < BM) ly[tid] = y[row0 + tid];

    f32x4 acc[4][4];
#pragma unroll
    for (int i = 0; i < 4; ++i)
#pragma unroll
        for (int j = 0; j < 4; ++j) acc[i][j] = (f32x4){0.f, 0.f, 0.f, 0.f};

    float zsq[4] = {0.f, 0.f, 0.f, 0.f};

    const float*  zb = z + (size_t)(row0 + sr) * HD + sq * 4;
    const __bf16* bb = mvbf + (size_t)br * HD + bq * 8;
    float4 a0 = *(const float4*)(zb);
    float4 a1 = *(const float4*)(zb + 32 * HD);
    float4 a2 = *(const float4*)(zb + 64 * HD);
    float4 a3 = *(const float4*)(zb + 96 * HD);
    bf16x8 b0 = *(const bf16x8*)(bb);
    bf16x8 b1 = *(const bf16x8*)(bb + 64 * HD);

    for (int kt = 0; kt < HD / BK; ++kt) {
        __syncthreads();  // previous iteration's frag reads done
        *(bf16x4*)&As[sr * SA + sq * 4]        = cvt4(a0);
        *(bf16x4*)&As[(sr + 32) * SA + sq * 4] = cvt4(a1);
        *(bf16x4*)&As[(sr + 64) * SA + sq * 4] = cvt4(a2);
        *(bf16x4*)&As[(sr + 96) * SA + sq * 4] = cvt4(a3);
        *(bf16x8*)&Bs[br * SA + bq * 8]        = b0;
        *(bf16x8*)&Bs[(br + 64) * SA + bq * 8] = b1;
        zsq[0] += dot4(a0); zsq[1] += dot4(a1);
        zsq[2] += dot4(a2); zsq[3] += dot4(a3);
        __syncthreads();
        if (kt + 1 < HD / BK) {   // prefetch next slab; overlaps MFMA below
            const float*  zn = zb + (kt + 1) * BK;
            const __bf16* bn = bb + (kt + 1) * BK;
            a0 = *(const float4*)(zn);
            a1 = *(const float4*)(zn + 32 * HD);
            a2 = *(const float4*)(zn + 64 * HD);
            a3 = *(const float4*)(zn + 96 * HD);
            b0 = *(const bf16x8*)(bn);
            b1 = *(const bf16x8*)(bn + 64 * HD);
        }
        const int ko = quad * 8;  // A[m][k=quad*8+j], B[n][k=quad*8+j]
        bf16x8 af[4], bfr[4];
#pragma unroll
        for (int i = 0; i < 4; ++i)
            af[i] = *(const bf16x8*)&As[(wr * 64 + i * 16 + l15) * SA + ko];
#pragma unroll
        for (int j = 0; j < 4; ++j)
            bfr[j] = *(const bf16x8*)&Bs[(wc * 64 + j * 16 + l15) * SA + ko];
#pragma unroll
        for (int i = 0; i < 4; ++i)
#pragma unroll
            for (int j = 0; j < 4; ++j)
                acc[i][j] = __builtin_amdgcn_mfma_f32_16x16x32_bf16(
                    af[i], bfr[j], acc[i][j], 0, 0, 0);
    }

    // reduce ||z||^2 across the 8 staging lanes sharing each row
#pragma unroll
    for (int o = 1; o < 8; o <<= 1)
#pragma unroll
        for (int i = 0; i < 4; ++i) zsq[i] += __shfl_xor(zsq[i], o, 64);
    if (sq == 0)
#pragma unroll
        for (int i = 0; i < 4; ++i) szn[sr + 32 * i] = zsq[i];
    __syncthreads();

    // epilogue: dist = ||z||^2 + ||m||^2 - 2*xp
    // C/D layout: col = lane&15, row = quad*4 + reg  [verified]
    f32x4 znv[4];
    int rcls[4][4];
#pragma unroll
    for (int i = 0; i < 4; ++i) {
        znv[i] = *(const f32x4*)&szn[wr * 64 + i * 16 + quad * 4];
#pragma unroll
        for (int reg = 0; reg < 4; ++reg)
            rcls[i][reg] = ly[wr * 64 + i * 16 + quad * 4 + reg];
    }
    float pm[4][4], ns[4][4];
#pragma unroll
    for (int i = 0; i < 4; ++i)
#pragma unroll
        for (int reg = 0; reg < 4; ++reg) { pm[i][reg] = 0.f; ns[i][reg] = 0.f; }

#pragma unroll
    for (int j = 0; j < 4; ++j) {
        const int c = wc * 64 + j * 16 + l15;
        const float mc = mn[c];
        const int ccls = c >> 3;
#pragma unroll
        for (int i = 0; i < 4; ++i) {
#pragma unroll
            for (int reg = 0; reg < 4; ++reg) {
                const int row = wr * 64 + i * 16 + quad * 4 + reg;
                float d = znv[i][reg] + mc - 2.f * acc[i][j][reg];
                float r = (d + 1.0f) * __builtin_amdgcn_rcpf(d + EPSV);
                float r2 = r * r;
                float s = r2 * r2 * r;   // ratio^5 == exp(log(ratio)/0.2)
                if (ccls == rcls[i][reg]) {
                    pm[i][reg] = fmaxf(pm[i][reg], s);
                    cd[(size_t)(row0 + row) * 8 + (c & 7)] = d;
                } else {
                    ns[i][reg] += s;
                }
            }
        }
    }
    // reduce across the 16 lanes (l15) of each quad group
#pragma unroll
    for (int o = 1; o < 16; o <<= 1) {
#pragma unroll
        for (int i = 0; i < 4; ++i)
#pragma unroll
            for (int reg = 0; reg < 4; ++reg) {
                pm[i][reg] = fmaxf(pm[i][reg], __shfl_xor(pm[i][reg], o, 64));
                ns[i][reg] += __shfl_xor(ns[i][reg], o, 64);
            }
    }
    if (l15 == 0) {
#pragma unroll
        for (int i = 0; i < 4; ++i)
#pragma unroll
            for (int reg = 0; reg < 4; ++reg) {
                const int row = wr * 64 + i * 16 + quad * 4 + reg;
                spm[wc][row] = pm[i][reg];
                sns[wc][row] = ns[i][reg];
            }
    }
    __syncthreads();
    if (tid < BM) {
        float p = fmaxf(spm[0][tid], spm[1][tid]);
        float nsum = sns[0][tid] + sns[1][tid];
        float li = logf((nsum + p) / p);   // = -log(pos/(neg+pos))
#pragma unroll
        for (int o = 1; o < 64; o <<= 1) li += __shfl_xor(li, o, 64);
        __shared__ float red[2];
        if ((tid & 63) == 0) red[tid >> 6] = li;
        __syncthreads();
        if (tid == 0) atomicAdd(lossAcc, red[0] + red[1]);
    }
}

// ---------------------------------------------------------------------------
// Kernel 3: stage-1 top-32. One block per (motif, 4096-row chunk).
// Gathers same-class candidates to LDS (expected ~256, cap 512), then 32
// block-argmax rounds with exact (value desc, index asc) ordering.
// ---------------------------------------------------------------------------
__global__ __launch_bounds__(256) void sel1_k(const int* __restrict__ y,
                                              const float* __restrict__ cd,
                                              float* __restrict__ s1v,
                                              int* __restrict__ s1i) {
    __shared__ float ldv[512];
    __shared__ int   lidx[512];
    __shared__ int   cnt;
    __shared__ float rv[4];
    __shared__ int   ri[4], rp[4];

    const int bid = blockIdx.x;
    const int j = bid >> 3, chunk = bid & 7;
    const int cls = j >> 3, m8 = j & 7;
    const int tid = threadIdx.x;
    if (tid == 0) cnt = 0;
    __syncthreads();

    const int base = chunk * 4096;
    for (int t = tid; t < 4096; t += 256) {
        const int i = base + t;
        if (y[i] == cls) {
            int p = atomicAdd(&cnt, 1);
            if (p < 512) { ldv[p] = cd[(size_t)i * 8 + m8]; lidx[p] = i; }
        }
    }
    __syncthreads();
    const int n = cnt < 512 ? cnt : 512;

    for (int r = 0; r < KSEL; ++r) {
        float bv = -INFINITY;
        int bi = 0x7fffffff, bp = -1;
        for (int p = tid; p < n; p += 256) {
            float v = ldv[p];
            int ix = lidx[p];
            if (v > bv || (v == bv && ix < bi)) { bv = v; bi = ix; bp = p; }
        }
#pragma unroll
        for (int o = 1; o < 64; o <<= 1) {
            float ov = __shfl_xor(bv, o, 64);
            int   oi = __shfl_xor(bi, o, 64);
            int   op = __shfl_xor(bp, o, 64);
            if (ov > bv || (ov == bv && oi < bi)) { bv = ov; bi = oi; bp = op; }
        }
        if ((tid & 63) == 0) { int w = tid >> 6; rv[w] = bv; ri[w] = bi; rp[w] = bp; }
        __syncthreads();
        if (tid == 0) {
            float xv = rv[0]; int xi = ri[0], xp = rp[0];
            for (int w = 1; w < 4; ++w)
                if (rv[w] > xv || (rv[w] == xv && ri[w] < xi)) {
                    xv = rv[w]; xi = ri[w]; xp = rp[w];
                }
            s1v[(size_t)bid * KSEL + r] = xv;
            s1i[(size_t)bid * KSEL + r] = xi;
            ldv[xp] = -INFINITY;
        }
        __syncthreads();
    }
}

// ---------------------------------------------------------------------------
// Kernel 4: merge 8x32 stage-1 candidates -> global top-32, gather-mean of
// selected z rows, tau-blend, write. Block 0 writes the final loss.
// ---------------------------------------------------------------------------
__global__ __launch_bounds__(256) void merge_k(
    const float* __restrict__ z, const float* __restrict__ mv,
    const float* __restrict__ s1v, const int* __restrict__ s1i,
    const float* __restrict__ lossAcc, float* __restrict__ out) {
    __shared__ float ldv[256];
    __shared__ int   lidx[256];
    __shared__ int   sel[KSEL];
    __shared__ float rv[4];
    __shared__ int   ri[4], rp[4];

    const int j = blockIdx.x;
    const int tid = threadIdx.x;
    ldv[tid] = s1v[(size_t)j * 256 + tid];
    lidx[tid] = s1i[(size_t)j * 256 + tid];
    __syncthreads();

    for (int r = 0; r < KSEL; ++r) {
        float bv = ldv[tid];
        int bi = lidx[tid], bp = tid;
#pragma unroll
        for (int o = 1; o < 64; o <<= 1) {
            float ov = __shfl_xor(bv, o, 64);
            int   oi = __shfl_xor(bi, o, 64);
            int   op = __shfl_xor(bp, o, 64);
            if (ov > bv || (ov == bv && oi < bi)) { bv = ov; bi = oi; bp = op; }
        }
        if ((tid & 63) == 0) { int w = tid >> 6; rv[w] = bv; ri[w] = bi; rp[w] = bp; }
        __syncthreads();
        if (tid == 0) {
            float xv = rv[0]; int xi = ri[0], xp = rp[0];
            for (int w = 1; w < 4; ++w)
                if (rv[w] > xv || (rv[w] == xv && ri[w] < xi)) {
                    xv = rv[w]; xi = ri[w]; xp = rp[w];
                }
            sel[r] = xi;
            ldv[xp] = -INFINITY;
        }
        __syncthreads();
    }

    for (int h = tid; h < HD; h += 256) {
        float s = 0.f;
#pragma unroll 8
        for (int k = 0; k < KSEL; ++k) s += z[(size_t)sel[k] * HD + h];
        out[1 + (size_t)j * HD + h] =
            0.99f * mv[(size_t)j * HD + h] + 0.01f * (s * (1.0f / KSEL));
    }
    if (j == 0 && tid == 0) out[0] = lossAcc[0] * (1.0f / NROWS);
}

// ---------------------------------------------------------------------------
extern "C" void kernel_launch(void* const* d_in, const int* in_sizes, int n_in,
                              void* d_out, int out_size, void* d_ws, size_t ws_size,
                              hipStream_t stream) {
    const float* z  = (const float*)d_in[0];
    const float* mv = (const float*)d_in[1];
    const int*   y  = (const int*)d_in[2];
    float* out = (float*)d_out;
    float* wsf = (float*)d_ws;
    float*  mn   = wsf + WS_MN;
    __bf16* mvbf = (__bf16*)(wsf + WS_MVBF);
    float*  cd   = wsf + WS_CD;
    float*  s1v  = wsf + WS_S1V;
    int*    s1i  = (int*)(wsf + WS_S1I);

    hipLaunchKernelGGL(prep_k,     dim3(NMOT),       dim3(256), 0, stream, mv, wsf, mvbf);
    hipLaunchKernelGGL(gemm_fused, dim3(NROWS / BM), dim3(256), 0, stream, z, mvbf, mn, cd, y, wsf);
    hipLaunchKernelGGL(sel1_k,     dim3(NMOT * 8),   dim3(256), 0, stream, y, cd, s1v, s1i);
    hipLaunchKernelGGL(merge_k,    dim3(NMOT),       dim3(256), 0, stream, z, mv, s1v, s1i, wsf, out);
}

// Round 4
// 239.771 us; speedup vs baseline: 1.2765x; 1.2765x over previous
//
#include <hip/hip_runtime.h>
#include <cstdint>
#include <cmath>

// Problem constants (fixed by setup_inputs)
#define NROWS 32768
#define HD    1024
#define NMOT  128
#define NCLS  16
#define KSEL  32
#define EPSV  1e-4f

typedef __attribute__((ext_vector_type(4))) float  f32x4;
typedef __attribute__((ext_vector_type(8))) __bf16 bf16x8;
typedef __attribute__((ext_vector_type(4))) __bf16 bf16x4;
typedef unsigned long long u64;

// ---- workspace layout (in floats) ----
// wsf[0]              : loss accumulator
// wsf[64..192)        : motif squared norms mn[128]
// wsf[256..65792)     : mvbf — mv converted to bf16 (128x1024)
// wsf[65792..327936)  : cd[32768][8] — per-row distances to its 8 same-class motifs
// wsf[327936..393472) : s1k[1024][32] — stage-1 top-32 packed u64 keys
#define WS_MN   64
#define WS_MVBF 256
#define WS_CD   65792
#define WS_S1K  327936

static __device__ __forceinline__ float dot4(float4 v) {
    return v.x * v.x + v.y * v.y + v.z * v.z + v.w * v.w;
}

static __device__ __forceinline__ bf16x4 cvt4(float4 v) {
    bf16x4 t;
    t[0] = (__bf16)v.x; t[1] = (__bf16)v.y; t[2] = (__bf16)v.z; t[3] = (__bf16)v.w;
    return t;
}

// packed key: ascending u64 order == (value descending, index ascending)
static __device__ __forceinline__ u64 pack_key(float v, int idx) {
    unsigned int b = __float_as_uint(v);
    unsigned int mo = (b & 0x80000000u) ? ~b : (b | 0x80000000u); // ascending map
    unsigned int khi = ~mo;                                      // descending
    return ((u64)khi << 32) | (unsigned int)idx;
}

// ---------------------------------------------------------------------------
// Kernel 1: motif norms + bf16 copy of mv + zero the loss accumulator
// ---------------------------------------------------------------------------
__global__ __launch_bounds__(256) void prep_k(const float* __restrict__ mv,
                                              float* __restrict__ wsf,
                                              __bf16* __restrict__ mvbf) {
    const int j = blockIdx.x;
    const int k = threadIdx.x * 4;           // 256 threads x 4 = 1024 = HD
    float4 v = *(const float4*)&mv[(size_t)j * HD + k];
    *(bf16x4*)&mvbf[(size_t)j * HD + k] = cvt4(v);
    float s = dot4(v);
#pragma unroll
    for (int o = 1; o < 64; o <<= 1) s += __shfl_xor(s, o, 64);
    __shared__ float red[4];
    if ((threadIdx.x & 63) == 0) red[threadIdx.x >> 6] = s;
    __syncthreads();
    if (threadIdx.x == 0) {
        wsf[WS_MN + j] = red[0] + red[1] + red[2] + red[3];
        if (j == 0) wsf[0] = 0.f;
    }
}

// ---------------------------------------------------------------------------
// Kernel 2: bf16-MFMA GEMM (z @ M^T), LDS double-buffered (1 barrier/slab),
// fused ||z||^2, distance epilogue, full contrastive loss, and compact
// same-class distance write cd[N][8].
// Tile: 64 rows x 128 cols, BK=32, 512 blocks (2/CU), 256 threads.
// ---------------------------------------------------------------------------
#define BM 64
#define BN 128
#define BK 32
#define SA 40   // padded LDS stride in bf16 elems (80B)

__global__ __launch_bounds__(256, 2) void gemm_fused(
    const float* __restrict__ z, const __bf16* __restrict__ mvbf,
    const float* __restrict__ mn, float* __restrict__ cd,
    const int* __restrict__ y, float* __restrict__ lossAcc) {
    __shared__ __bf16 As[2][BM * SA];
    __shared__ __bf16 Bs[2][BN * SA];
    __shared__ float  szn[BM];
    __shared__ int    ly[BM];
    __shared__ float  spm[2][BM];
    __shared__ float  sns[2][BM];

    const int tid  = threadIdx.x;
    const int row0 = blockIdx.x * BM;
    const int lane = tid & 63;
    const int wave = tid >> 6;
    const int wr   = wave >> 1;   // 0..1 : 32-row strip
    const int wc   = wave & 1;    // 0..1 : 64-col strip
    const int l15  = lane & 15;
    const int quad = lane >> 4;

    const int sq = tid & 7;       // A staging: float4 slot in 32-wide k slab
    const int sr = tid >> 3;      // A staging: row 0..31 (rows sr, sr+32)
    const int bq = tid & 3;       // B staging: 16B chunk in k-slab
    const int br = tid >> 2;      // B staging: row 0..63 (rows br, br+64)

    if (tid < BM) ly[tid] = y[row0 + tid];

    f32x4 acc[2][4];
#pragma unroll
    for (int i = 0; i < 2; ++i)
#pragma unroll
        for (int j = 0; j < 4; ++j) acc[i][j] = (f32x4){0.f, 0.f, 0.f, 0.f};

    float zsq0 = 0.f, zsq1 = 0.f;

    const float*  zb = z + (size_t)(row0 + sr) * HD + sq * 4;
    const __bf16* bb = mvbf + (size_t)br * HD + bq * 8;

    // slab 0: load + write buf0
    float4 a0 = *(const float4*)(zb);
    float4 a1 = *(const float4*)(zb + 32 * HD);
    bf16x8 b0 = *(const bf16x8*)(bb);
    bf16x8 b1 = *(const bf16x8*)(bb + 64 * HD);
    *(bf16x4*)&As[0][sr * SA + sq * 4]        = cvt4(a0);
    *(bf16x4*)&As[0][(sr + 32) * SA + sq * 4] = cvt4(a1);
    *(bf16x8*)&Bs[0][br * SA + bq * 8]        = b0;
    *(bf16x8*)&Bs[0][(br + 64) * SA + bq * 8] = b1;
    zsq0 += dot4(a0); zsq1 += dot4(a1);
    // slab 1 loads in flight
    a0 = *(const float4*)(zb + BK);
    a1 = *(const float4*)(zb + BK + 32 * HD);
    b0 = *(const bf16x8*)(bb + BK);
    b1 = *(const bf16x8*)(bb + BK + 64 * HD);

    for (int kt = 0; kt < HD / BK; ++kt) {
        __syncthreads();   // buf[kt&1] ready; buf[(kt+1)&1] fully consumed
        if (kt + 1 < HD / BK) {
            const int w = (kt + 1) & 1;
            *(bf16x4*)&As[w][sr * SA + sq * 4]        = cvt4(a0);
            *(bf16x4*)&As[w][(sr + 32) * SA + sq * 4] = cvt4(a1);
            *(bf16x8*)&Bs[w][br * SA + bq * 8]        = b0;
            *(bf16x8*)&Bs[w][(br + 64) * SA + bq * 8] = b1;
            zsq0 += dot4(a0); zsq1 += dot4(a1);
            if (kt + 2 < HD / BK) {   // issue slab kt+2; consumed next iter
                const float*  zn = zb + (kt + 2) * BK;
                const __bf16* bn = bb + (kt + 2) * BK;
                a0 = *(const float4*)(zn);
                a1 = *(const float4*)(zn + 32 * HD);
                b0 = *(const bf16x8*)(bn);
                b1 = *(const bf16x8*)(bn + 64 * HD);
            }
        }
        const int rb = kt & 1;
        const int ko = quad * 8;  // A[m][k=quad*8+j], B[n][k=quad*8+j]
        bf16x8 af[2], bfr[4];
#pragma unroll
        for (int i = 0; i < 2; ++i)
            af[i] = *(const bf16x8*)&As[rb][(wr * 32 + i * 16 + l15) * SA + ko];
#pragma unroll
        for (int j = 0; j < 4; ++j)
            bfr[j] = *(const bf16x8*)&Bs[rb][(wc * 64 + j * 16 + l15) * SA + ko];
#pragma unroll
        for (int i = 0; i < 2; ++i)
#pragma unroll
            for (int j = 0; j < 4; ++j)
                acc[i][j] = __builtin_amdgcn_mfma_f32_16x16x32_bf16(
                    af[i], bfr[j], acc[i][j], 0, 0, 0);
    }

    // reduce ||z||^2 across the 8 staging lanes sharing each row
#pragma unroll
    for (int o = 1; o < 8; o <<= 1) {
        zsq0 += __shfl_xor(zsq0, o, 64);
        zsq1 += __shfl_xor(zsq1, o, 64);
    }
    if (sq == 0) { szn[sr] = zsq0; szn[sr + 32] = zsq1; }
    __syncthreads();

    // epilogue: dist = ||z||^2 + ||m||^2 - 2*xp
    // C/D layout: col = lane&15, row = quad*4 + reg  [verified]
    f32x4 znv[2];
    int rcls[2][4];
#pragma unroll
    for (int i = 0; i < 2; ++i) {
        znv[i] = *(const f32x4*)&szn[wr * 32 + i * 16 + quad * 4];
#pragma unroll
        for (int reg = 0; reg < 4; ++reg)
            rcls[i][reg] = ly[wr * 32 + i * 16 + quad * 4 + reg];
    }
    float pm[2][4], ns[2][4];
#pragma unroll
    for (int i = 0; i < 2; ++i)
#pragma unroll
        for (int reg = 0; reg < 4; ++reg) { pm[i][reg] = 0.f; ns[i][reg] = 0.f; }

#pragma unroll
    for (int j = 0; j < 4; ++j) {
        const int c = wc * 64 + j * 16 + l15;
        const float mc = mn[c];
        const int ccls = c >> 3;
#pragma unroll
        for (int i = 0; i < 2; ++i) {
#pragma unroll
            for (int reg = 0; reg < 4; ++reg) {
                const int row = wr * 32 + i * 16 + quad * 4 + reg;
                float d = znv[i][reg] + mc - 2.f * acc[i][j][reg];
                float r = (d + 1.0f) * __builtin_amdgcn_rcpf(d + EPSV);
                float r2 = r * r;
                float s = r2 * r2 * r;   // ratio^5 == exp(log(ratio)/0.2)
                if (ccls == rcls[i][reg]) {
                    pm[i][reg] = fmaxf(pm[i][reg], s);
                    cd[(size_t)(row0 + row) * 8 + (c & 7)] = d;
                } else {
                    ns[i][reg] += s;
                }
            }
        }
    }
    // reduce across the 16 lanes (l15) of each quad group
#pragma unroll
    for (int o = 1; o < 16; o <<= 1) {
#pragma unroll
        for (int i = 0; i < 2; ++i)
#pragma unroll
            for (int reg = 0; reg < 4; ++reg) {
                pm[i][reg] = fmaxf(pm[i][reg], __shfl_xor(pm[i][reg], o, 64));
                ns[i][reg] += __shfl_xor(ns[i][reg], o, 64);
            }
    }
    if (l15 == 0) {
#pragma unroll
        for (int i = 0; i < 2; ++i)
#pragma unroll
            for (int reg = 0; reg < 4; ++reg) {
                const int row = wr * 32 + i * 16 + quad * 4 + reg;
                spm[wc][row] = pm[i][reg];
                sns[wc][row] = ns[i][reg];
            }
    }
    __syncthreads();
    if (tid < BM) {   // wave 0 only (BM=64)
        float p = fmaxf(spm[0][tid], spm[1][tid]);
        float nsum = sns[0][tid] + sns[1][tid];
        float li = logf((nsum + p) / p);   // = -log(pos/(neg+pos))
#pragma unroll
        for (int o = 1; o < 64; o <<= 1) li += __shfl_xor(li, o, 64);
        if (tid == 0) atomicAdd(lossAcc, li);
    }
}

// ---------------------------------------------------------------------------
// Kernel 3: stage-1 top-32. One block per (motif, 4096-row chunk).
// Ballot-compacts same-class candidates as packed u64 keys, pads to 512,
// bitonic-sorts ascending (== value desc, idx asc), writes first 32 keys.
// ---------------------------------------------------------------------------
__global__ __launch_bounds__(256) void sel1_k(const int* __restrict__ y,
                                              const float* __restrict__ cd,
                                              u64* __restrict__ s1k) {
    __shared__ u64 keys[512];
    __shared__ int cnt;

    const int bid = blockIdx.x;
    const int j = bid >> 3, chunk = bid & 7;
    const int cls = j >> 3, m8 = j & 7;
    const int tid = threadIdx.x;
    const int lane = tid & 63;
    if (tid == 0) cnt = 0;
    __syncthreads();

    const int base = chunk * 4096;
#pragma unroll
    for (int t = 0; t < 16; ++t) {
        const int i = base + t * 256 + tid;
        const bool pred = (y[i] == cls);
        const u64 m = __ballot(pred);
        int wbase = 0;
        if (lane == 0 && m) wbase = atomicAdd(&cnt, (int)__popcll(m));
        wbase = __shfl(wbase, 0, 64);
        if (pred) {
            const int p = wbase + (int)__popcll(m & ((1ull << lane) - 1ull));
            if (p < 512) keys[p] = pack_key(cd[(size_t)i * 8 + m8], i);
        }
    }
    __syncthreads();
    const int n = cnt < 512 ? cnt : 512;
    for (int t = tid; t < 512; t += 256)
        if (t >= n) keys[t] = ~0ull;   // sorts last
    __syncthreads();

    // bitonic sort, 512 elems, 256 threads = 1 pair each, ascending
    for (int k = 2; k <= 512; k <<= 1) {
        for (int jj = k >> 1; jj > 0; jj >>= 1) {
            const int i  = ((tid & ~(jj - 1)) << 1) | (tid & (jj - 1));
            const int ix = i | jj;
            const u64 A = keys[i], B = keys[ix];
            const bool up = ((i & k) == 0);
            if ((A > B) == up) { keys[i] = B; keys[ix] = A; }
            __syncthreads();
        }
    }
    if (tid < KSEL) s1k[(size_t)bid * KSEL + tid] = keys[tid];
}

// ---------------------------------------------------------------------------
// Kernel 4: merge 8x32 stage-1 keys -> global top-32 (bitonic-256, redundant
// per column-quarter), gather-mean of selected z rows, tau-blend, write.
// 512 blocks: (motif j = b>>2, column quarter q = b&3).
// ---------------------------------------------------------------------------
__global__ __launch_bounds__(256) void merge_k(
    const float* __restrict__ z, const float* __restrict__ mv,
    const u64* __restrict__ s1k, const float* __restrict__ lossAcc,
    float* __restrict__ out) {
    __shared__ u64 keys[256];
    __shared__ int sel[KSEL];

    const int b = blockIdx.x;
    const int j = b >> 2, q = b & 3;
    const int tid = threadIdx.x;
    keys[tid] = s1k[(size_t)j * 256 + tid];
    __syncthreads();

    // bitonic sort, 256 elems, threads 0..127 act (1 pair each), ascending
    for (int k = 2; k <= 256; k <<= 1) {
        for (int jj = k >> 1; jj > 0; jj >>= 1) {
            if (tid < 128) {
                const int i  = ((tid & ~(jj - 1)) << 1) | (tid & (jj - 1));
                const int ix = i | jj;
                const u64 A = keys[i], B = keys[ix];
                const bool up = ((i & k) == 0);
                if ((A > B) == up) { keys[i] = B; keys[ix] = A; }
            }
            __syncthreads();
        }
    }
    if (tid < KSEL) sel[tid] = (int)(keys[tid] & 0xFFFFFFFFu);
    __syncthreads();

    const int h = q * 256 + tid;
    float s = 0.f;
#pragma unroll 8
    for (int r = 0; r < KSEL; ++r) s += z[(size_t)sel[r] * HD + h];
    out[1 + (size_t)j * HD + h] =
        0.99f * mv[(size_t)j * HD + h] + 0.01f * (s * (1.0f / KSEL));
    if (b == 0 && tid == 0) out[0] = lossAcc[0] * (1.0f / NROWS);
}

// ---------------------------------------------------------------------------
extern "C" void kernel_launch(void* const* d_in, const int* in_sizes, int n_in,
                              void* d_out, int out_size, void* d_ws, size_t ws_size,
                              hipStream_t stream) {
    const float* z  = (const float*)d_in[0];
    const float* mv = (const float*)d_in[1];
    const int*   y  = (const int*)d_in[2];
    float* out = (float*)d_out;
    float* wsf = (float*)d_ws;
    float*  mn   = wsf + WS_MN;
    __bf16* mvbf = (__bf16*)(wsf + WS_MVBF);
    float*  cd   = wsf + WS_CD;
    u64*    s1k  = (u64*)(wsf + WS_S1K);

    hipLaunchKernelGGL(prep_k,     dim3(NMOT),       dim3(256), 0, stream, mv, wsf, mvbf);
    hipLaunchKernelGGL(gemm_fused, dim3(NROWS / BM), dim3(256), 0, stream, z, mvbf, mn, cd, y, wsf);
    hipLaunchKernelGGL(sel1_k,     dim3(NMOT * 8),   dim3(256), 0, stream, y, cd, s1k);
    hipLaunchKernelGGL(merge_k,    dim3(NMOT * 4),   dim3(256), 0, stream, z, mv, s1k, wsf, out);
}

// Round 5
// 236.731 us; speedup vs baseline: 1.2929x; 1.0128x over previous
//
#include <hip/hip_runtime.h>
#include <cstdint>
#include <cmath>

// Problem constants (fixed by setup_inputs)
#define NROWS 32768
#define HD    1024
#define NMOT  128
#define NCLS  16
#define KSEL  32
#define EPSV  1e-4f

typedef __attribute__((ext_vector_type(4))) float  f32x4;
typedef __attribute__((ext_vector_type(8))) __bf16 bf16x8;
typedef __attribute__((ext_vector_type(4))) __bf16 bf16x4;
typedef unsigned long long u64;

// ---- workspace layout (in floats) ----
// wsf[0]              : loss accumulator
// wsf[64..192)        : motif squared norms mn[128]
// wsf[256..65792)     : mvbf — mv converted to bf16 (128x1024)
// wsf[65792..327936)  : cd[32768][8] — per-row distances to its 8 same-class motifs
// wsf[327936..393472) : s1k[1024][32] — stage-1 top-32 packed u64 keys
#define WS_MN   64
#define WS_MVBF 256
#define WS_CD   65792
#define WS_S1K  327936

static __device__ __forceinline__ float dot4(float4 v) {
    return v.x * v.x + v.y * v.y + v.z * v.z + v.w * v.w;
}

static __device__ __forceinline__ bf16x4 cvt4(float4 v) {
    bf16x4 t;
    t[0] = (__bf16)v.x; t[1] = (__bf16)v.y; t[2] = (__bf16)v.z; t[3] = (__bf16)v.w;
    return t;
}

// packed key: ascending u64 order == (value descending, index ascending)
static __device__ __forceinline__ u64 pack_key(float v, int idx) {
    unsigned int b = __float_as_uint(v);
    unsigned int mo = (b & 0x80000000u) ? ~b : (b | 0x80000000u); // ascending map
    unsigned int khi = ~mo;                                      // descending
    return ((u64)khi << 32) | (unsigned int)idx;
}

// ---------------------------------------------------------------------------
// Kernel 1: motif norms + bf16 copy of mv + zero the loss accumulator
// ---------------------------------------------------------------------------
__global__ __launch_bounds__(256) void prep_k(const float* __restrict__ mv,
                                              float* __restrict__ wsf,
                                              __bf16* __restrict__ mvbf) {
    const int j = blockIdx.x;
    const int k = threadIdx.x * 4;           // 256 threads x 4 = 1024 = HD
    float4 v = *(const float4*)&mv[(size_t)j * HD + k];
    *(bf16x4*)&mvbf[(size_t)j * HD + k] = cvt4(v);
    float s = dot4(v);
#pragma unroll
    for (int o = 1; o < 64; o <<= 1) s += __shfl_xor(s, o, 64);
    __shared__ float red[4];
    if ((threadIdx.x & 63) == 0) red[threadIdx.x >> 6] = s;
    __syncthreads();
    if (threadIdx.x == 0) {
        wsf[WS_MN + j] = red[0] + red[1] + red[2] + red[3];
        if (j == 0) wsf[0] = 0.f;
    }
}

// ---------------------------------------------------------------------------
// Kernel 2: bf16-MFMA GEMM (z @ M^T), LDS double-buffered, register ring of
// 4 k-slabs (loads issued ~4 iterations ahead of consumption to cover the
// ~900cy HBM latency), single barrier per slab. Fused ||z||^2, distance
// epilogue, full contrastive loss, compact same-class distance write cd[N][8].
// Tile: 64 rows x 128 cols, BK=32, 512 blocks (2/CU), 256 threads.
// ---------------------------------------------------------------------------
#define BM 64
#define BN 128
#define BK 32
#define NS (HD / BK)   // 32 k-slabs
#define SA 40          // padded LDS stride in bf16 elems (80B)

__global__ __launch_bounds__(256, 2) void gemm_fused(
    const float* __restrict__ z, const __bf16* __restrict__ mvbf,
    const float* __restrict__ mn, float* __restrict__ cd,
    const int* __restrict__ y, float* __restrict__ lossAcc) {
    __shared__ __bf16 As[2][BM * SA];
    __shared__ __bf16 Bs[2][BN * SA];
    __shared__ float  szn[BM];
    __shared__ int    ly[BM];
    __shared__ float  spm[2][BM];
    __shared__ float  sns[2][BM];

    const int tid  = threadIdx.x;
    const int row0 = blockIdx.x * BM;
    const int lane = tid & 63;
    const int wave = tid >> 6;
    const int wr   = wave >> 1;   // 0..1 : 32-row strip
    const int wc   = wave & 1;    // 0..1 : 64-col strip
    const int l15  = lane & 15;
    const int quad = lane >> 4;

    const int sq = tid & 7;       // A staging: float4 slot in 32-wide k slab
    const int sr = tid >> 3;      // A staging: row 0..31 (rows sr, sr+32)
    const int bq = tid & 3;       // B staging: 16B chunk in k-slab
    const int br = tid >> 2;      // B staging: row 0..63 (rows br, br+64)

    if (tid < BM) ly[tid] = y[row0 + tid];

    f32x4 acc[2][4];
#pragma unroll
    for (int i = 0; i < 2; ++i)
#pragma unroll
        for (int j = 0; j < 4; ++j) acc[i][j] = (f32x4){0.f, 0.f, 0.f, 0.f};

    float zsq0 = 0.f, zsq1 = 0.f;

    const float*  zb = z + (size_t)(row0 + sr) * HD + sq * 4;
    const __bf16* bb = mvbf + (size_t)br * HD + bq * 8;

    // ---- register ring: 4 slabs in flight ----
    float4 ra0[4], ra1[4];
    bf16x8 rb0[4], rb1[4];
#pragma unroll
    for (int s = 0; s < 4; ++s) {          // issue slabs 0..3
        ra0[s] = *(const float4*)(zb + s * BK);
        ra1[s] = *(const float4*)(zb + s * BK + 32 * HD);
        rb0[s] = *(const bf16x8*)(bb + s * BK);
        rb1[s] = *(const bf16x8*)(bb + s * BK + 64 * HD);
    }
    // stage slab 0 into buf0, then reuse slot 0 for slab 4
    *(bf16x4*)&As[0][sr * SA + sq * 4]        = cvt4(ra0[0]);
    *(bf16x4*)&As[0][(sr + 32) * SA + sq * 4] = cvt4(ra1[0]);
    *(bf16x8*)&Bs[0][br * SA + bq * 8]        = rb0[0];
    *(bf16x8*)&Bs[0][(br + 64) * SA + bq * 8] = rb1[0];
    zsq0 += dot4(ra0[0]); zsq1 += dot4(ra1[0]);
    ra0[0] = *(const float4*)(zb + 4 * BK);
    ra1[0] = *(const float4*)(zb + 4 * BK + 32 * HD);
    rb0[0] = *(const bf16x8*)(bb + 4 * BK);
    rb1[0] = *(const bf16x8*)(bb + 4 * BK + 64 * HD);
    __syncthreads();

    // main loop: iter kt consumes LDS slab kt, stages slab kt+1 (ring slot
    // (kt+1)%4), issues loads for slab kt+5 into the freed slot.
    for (int it = 0; it < NS / 4; ++it) {
#pragma unroll
        for (int u = 0; u < 4; ++u) {
            const int kt = it * 4 + u;
            const int rbuf = kt & 1;
            const int ko = quad * 8;   // A[m][k=quad*8+j], B[n][k=quad*8+j]
            // step1: fragment reads for slab kt
            bf16x8 af[2], bfr[4];
#pragma unroll
            for (int i = 0; i < 2; ++i)
                af[i] = *(const bf16x8*)&As[rbuf][(wr * 32 + i * 16 + l15) * SA + ko];
#pragma unroll
            for (int j = 0; j < 4; ++j)
                bfr[j] = *(const bf16x8*)&Bs[rbuf][(wc * 64 + j * 16 + l15) * SA + ko];
            // step2: stage slab kt+1 from ring, issue loads for slab kt+5
            if (kt + 1 < NS) {
                const int w = (kt + 1) & 1;
                const int s = (kt + 1) & 3;
                *(bf16x4*)&As[w][sr * SA + sq * 4]        = cvt4(ra0[s]);
                *(bf16x4*)&As[w][(sr + 32) * SA + sq * 4] = cvt4(ra1[s]);
                *(bf16x8*)&Bs[w][br * SA + bq * 8]        = rb0[s];
                *(bf16x8*)&Bs[w][(br + 64) * SA + bq * 8] = rb1[s];
                zsq0 += dot4(ra0[s]); zsq1 += dot4(ra1[s]);
                if (kt + 5 < NS) {
                    const float*  zn = zb + (kt + 5) * BK;
                    const __bf16* bn = bb + (kt + 5) * BK;
                    ra0[s] = *(const float4*)(zn);
                    ra1[s] = *(const float4*)(zn + 32 * HD);
                    rb0[s] = *(const bf16x8*)(bn);
                    rb1[s] = *(const bf16x8*)(bn + 64 * HD);
                }
            }
            // step3: MFMA on slab kt
#pragma unroll
            for (int i = 0; i < 2; ++i)
#pragma unroll
                for (int j = 0; j < 4; ++j)
                    acc[i][j] = __builtin_amdgcn_mfma_f32_16x16x32_bf16(
                        af[i], bfr[j], acc[i][j], 0, 0, 0);
            // step4: one barrier per slab
            __syncthreads();
        }
    }

    // reduce ||z||^2 across the 8 staging lanes sharing each row
#pragma unroll
    for (int o = 1; o < 8; o <<= 1) {
        zsq0 += __shfl_xor(zsq0, o, 64);
        zsq1 += __shfl_xor(zsq1, o, 64);
    }
    if (sq == 0) { szn[sr] = zsq0; szn[sr + 32] = zsq1; }
    __syncthreads();

    // epilogue: dist = ||z||^2 + ||m||^2 - 2*xp
    // C/D layout: col = lane&15, row = quad*4 + reg  [verified]
    f32x4 znv[2];
    int rcls[2][4];
#pragma unroll
    for (int i = 0; i < 2; ++i) {
        znv[i] = *(const f32x4*)&szn[wr * 32 + i * 16 + quad * 4];
#pragma unroll
        for (int reg = 0; reg < 4; ++reg)
            rcls[i][reg] = ly[wr * 32 + i * 16 + quad * 4 + reg];
    }
    float pm[2][4], ns[2][4];
#pragma unroll
    for (int i = 0; i < 2; ++i)
#pragma unroll
        for (int reg = 0; reg < 4; ++reg) { pm[i][reg] = 0.f; ns[i][reg] = 0.f; }

#pragma unroll
    for (int j = 0; j < 4; ++j) {
        const int c = wc * 64 + j * 16 + l15;
        const float mc = mn[c];
        const int ccls = c >> 3;
#pragma unroll
        for (int i = 0; i < 2; ++i) {
#pragma unroll
            for (int reg = 0; reg < 4; ++reg) {
                const int row = wr * 32 + i * 16 + quad * 4 + reg;
                float d = znv[i][reg] + mc - 2.f * acc[i][j][reg];
                float r = (d + 1.0f) * __builtin_amdgcn_rcpf(d + EPSV);
                float r2 = r * r;
                float s = r2 * r2 * r;   // ratio^5 == exp(log(ratio)/0.2)
                if (ccls == rcls[i][reg]) {
                    pm[i][reg] = fmaxf(pm[i][reg], s);
                    cd[(size_t)(row0 + row) * 8 + (c & 7)] = d;
                } else {
                    ns[i][reg] += s;
                }
            }
        }
    }
    // reduce across the 16 lanes (l15) of each quad group
#pragma unroll
    for (int o = 1; o < 16; o <<= 1) {
#pragma unroll
        for (int i = 0; i < 2; ++i)
#pragma unroll
            for (int reg = 0; reg < 4; ++reg) {
                pm[i][reg] = fmaxf(pm[i][reg], __shfl_xor(pm[i][reg], o, 64));
                ns[i][reg] += __shfl_xor(ns[i][reg], o, 64);
            }
    }
    if (l15 == 0) {
#pragma unroll
        for (int i = 0; i < 2; ++i)
#pragma unroll
            for (int reg = 0; reg < 4; ++reg) {
                const int row = wr * 32 + i * 16 + quad * 4 + reg;
                spm[wc][row] = pm[i][reg];
                sns[wc][row] = ns[i][reg];
            }
    }
    __syncthreads();
    if (tid < BM) {   // wave 0 only (BM=64)
        float p = fmaxf(spm[0][tid], spm[1][tid]);
        float nsum = sns[0][tid] + sns[1][tid];
        float li = logf((nsum + p) / p);   // = -log(pos/(neg+pos))
#pragma unroll
        for (int o = 1; o < 64; o <<= 1) li += __shfl_xor(li, o, 64);
        if (tid == 0) atomicAdd(lossAcc, li);
    }
}

// ---------------------------------------------------------------------------
// Kernel 3: stage-1 top-32. One block per (motif, 4096-row chunk).
// Ballot-compacts same-class candidates as packed u64 keys, pads to 512,
// bitonic-sorts ascending (== value desc, idx asc), writes first 32 keys.
// ---------------------------------------------------------------------------
__global__ __launch_bounds__(256) void sel1_k(const int* __restrict__ y,
                                              const float* __restrict__ cd,
                                              u64* __restrict__ s1k) {
    __shared__ u64 keys[512];
    __shared__ int cnt;

    const int bid = blockIdx.x;
    const int j = bid >> 3, chunk = bid & 7;
    const int cls = j >> 3, m8 = j & 7;
    const int tid = threadIdx.x;
    const int lane = tid & 63;
    if (tid == 0) cnt = 0;
    __syncthreads();

    const int base = chunk * 4096;
#pragma unroll
    for (int t = 0; t < 16; ++t) {
        const int i = base + t * 256 + tid;
        const bool pred = (y[i] == cls);
        const u64 m = __ballot(pred);
        int wbase = 0;
        if (lane == 0 && m) wbase = atomicAdd(&cnt, (int)__popcll(m));
        wbase = __shfl(wbase, 0, 64);
        if (pred) {
            const int p = wbase + (int)__popcll(m & ((1ull << lane) - 1ull));
            if (p < 512) keys[p] = pack_key(cd[(size_t)i * 8 + m8], i);
        }
    }
    __syncthreads();
    const int n = cnt < 512 ? cnt : 512;
    for (int t = tid; t < 512; t += 256)
        if (t >= n) keys[t] = ~0ull;   // sorts last
    __syncthreads();

    // bitonic sort, 512 elems, 256 threads = 1 pair each, ascending
    for (int k = 2; k <= 512; k <<= 1) {
        for (int jj = k >> 1; jj > 0; jj >>= 1) {
            const int i  = ((tid & ~(jj - 1)) << 1) | (tid & (jj - 1));
            const int ix = i | jj;
            const u64 A = keys[i], B = keys[ix];
            const bool up = ((i & k) == 0);
            if ((A > B) == up) { keys[i] = B; keys[ix] = A; }
            __syncthreads();
        }
    }
    if (tid < KSEL) s1k[(size_t)bid * KSEL + tid] = keys[tid];
}

// ---------------------------------------------------------------------------
// Kernel 4: merge 8x32 stage-1 keys -> global top-32 (bitonic-256, redundant
// per column-quarter), gather-mean of selected z rows, tau-blend, write.
// 512 blocks: (motif j = b>>2, column quarter q = b&3).
// ---------------------------------------------------------------------------
__global__ __launch_bounds__(256) void merge_k(
    const float* __restrict__ z, const float* __restrict__ mv,
    const u64* __restrict__ s1k, const float* __restrict__ lossAcc,
    float* __restrict__ out) {
    __shared__ u64 keys[256];
    __shared__ int sel[KSEL];

    const int b = blockIdx.x;
    const int j = b >> 2, q = b & 3;
    const int tid = threadIdx.x;
    keys[tid] = s1k[(size_t)j * 256 + tid];
    __syncthreads();

    // bitonic sort, 256 elems, threads 0..127 act (1 pair each), ascending
    for (int k = 2; k <= 256; k <<= 1) {
        for (int jj = k >> 1; jj > 0; jj >>= 1) {
            if (tid < 128) {
                const int i  = ((tid & ~(jj - 1)) << 1) | (tid & (jj - 1));
                const int ix = i | jj;
                const u64 A = keys[i], B = keys[ix];
                const bool up = ((i & k) == 0);
                if ((A > B) == up) { keys[i] = B; keys[ix] = A; }
            }
            __syncthreads();
        }
    }
    if (tid < KSEL) sel[tid] = (int)(keys[tid] & 0xFFFFFFFFu);
    __syncthreads();

    const int h = q * 256 + tid;
    float s = 0.f;
#pragma unroll 8
    for (int r = 0; r < KSEL; ++r) s += z[(size_t)sel[r] * HD + h];
    out[1 + (size_t)j * HD + h] =
        0.99f * mv[(size_t)j * HD + h] + 0.01f * (s * (1.0f / KSEL));
    if (b == 0 && tid == 0) out[0] = lossAcc[0] * (1.0f / NROWS);
}

// ---------------------------------------------------------------------------
extern "C" void kernel_launch(void* const* d_in, const int* in_sizes, int n_in,
                              void* d_out, int out_size, void* d_ws, size_t ws_size,
                              hipStream_t stream) {
    const float* z  = (const float*)d_in[0];
    const float* mv = (const float*)d_in[1];
    const int*   y  = (const int*)d_in[2];
    float* out = (float*)d_out;
    float* wsf = (float*)d_ws;
    float*  mn   = wsf + WS_MN;
    __bf16* mvbf = (__bf16*)(wsf + WS_MVBF);
    float*  cd   = wsf + WS_CD;
    u64*    s1k  = (u64*)(wsf + WS_S1K);

    hipLaunchKernelGGL(prep_k,     dim3(NMOT),       dim3(256), 0, stream, mv, wsf, mvbf);
    hipLaunchKernelGGL(gemm_fused, dim3(NROWS / BM), dim3(256), 0, stream, z, mvbf, mn, cd, y, wsf);
    hipLaunchKernelGGL(sel1_k,     dim3(NMOT * 8),   dim3(256), 0, stream, y, cd, s1k);
    hipLaunchKernelGGL(merge_k,    dim3(NMOT * 4),   dim3(256), 0, stream, z, mv, s1k, wsf, out);
}

// Round 6
// 231.389 us; speedup vs baseline: 1.3227x; 1.0231x over previous
//
#include <hip/hip_runtime.h>
#include <cstdint>
#include <cmath>

// Problem constants (fixed by setup_inputs)
#define NROWS 32768
#define HD    1024
#define NMOT  128
#define NCLS  16
#define KSEL  32
#define EPSV  1e-4f

typedef __attribute__((ext_vector_type(4))) float  f32x4;
typedef __attribute__((ext_vector_type(8))) __bf16 bf16x8;
typedef __attribute__((ext_vector_type(4))) __bf16 bf16x4;
typedef unsigned long long u64;

// ---- workspace layout (in float slots) ----
// wsf[0]               : loss accumulator
// wsf[64..192)         : motif squared norms mn[128]
// wsf[256..65792)      : mvbf — mv converted to bf16 (128x1024)
// wsf[65792..327936)   : cd[32768][8] — per-row dist to its 8 same-class motifs
// wsf[327936..459008)  : s1k[128][512] — stage-1 top-32 keys per (motif,chunk)
// wsf[459008..524544)  : clist[256][256] — row indices per (class,chunk)
// wsf[524544..524800)  : ccnt[256] — candidate count per (class,chunk)
#define WS_MN   64
#define WS_MVBF 256
#define WS_CD   65792
#define WS_S1K  327936
#define WS_CL   459008
#define WS_CCNT 524544
#define CAPC    256     // per-(class,2048-row-chunk) candidate cap: mean 128, sigma 11

static __device__ __forceinline__ float dot4(float4 v) {
    return v.x * v.x + v.y * v.y + v.z * v.z + v.w * v.w;
}

static __device__ __forceinline__ bf16x4 cvt4(float4 v) {
    bf16x4 t;
    t[0] = (__bf16)v.x; t[1] = (__bf16)v.y; t[2] = (__bf16)v.z; t[3] = (__bf16)v.w;
    return t;
}

// packed key: ascending u64 order == (value descending, index ascending)
static __device__ __forceinline__ u64 pack_key(float v, int idx) {
    unsigned int b = __float_as_uint(v);
    unsigned int mo = (b & 0x80000000u) ? ~b : (b | 0x80000000u); // ascending map
    unsigned int khi = ~mo;                                      // descending
    return ((u64)khi << 32) | (unsigned int)idx;
}

// ---------------------------------------------------------------------------
// Kernel 1 (fused): blocks 0..127  -> motif norms + bf16 copy of mv (+zero loss)
//                   blocks 128..383 -> per-(class,chunk) candidate-index lists
// ---------------------------------------------------------------------------
__global__ __launch_bounds__(256) void prep_k(const float* __restrict__ mv,
                                              const int* __restrict__ y,
                                              float* __restrict__ wsf,
                                              __bf16* __restrict__ mvbf,
                                              int* __restrict__ clist,
                                              int* __restrict__ ccnt) {
    const int b = blockIdx.x;
    const int tid = threadIdx.x;
    if (b < NMOT) {
        const int k = tid * 4;               // 256 threads x 4 = 1024 = HD
        float4 v = *(const float4*)&mv[(size_t)b * HD + k];
        *(bf16x4*)&mvbf[(size_t)b * HD + k] = cvt4(v);
        float s = dot4(v);
#pragma unroll
        for (int o = 1; o < 64; o <<= 1) s += __shfl_xor(s, o, 64);
        __shared__ float red[4];
        if ((tid & 63) == 0) red[tid >> 6] = s;
        __syncthreads();
        if (tid == 0) {
            wsf[WS_MN + b] = red[0] + red[1] + red[2] + red[3];
            if (b == 0) wsf[0] = 0.f;
        }
    } else {
        __shared__ int cnt;
        const int lid = b - NMOT;            // 0..255
        const int cls = lid >> 4, chunk = lid & 15;
        const int lane = tid & 63;
        if (tid == 0) cnt = 0;
        __syncthreads();
        const int base = chunk * 2048;
#pragma unroll
        for (int t = 0; t < 8; ++t) {
            const int i = base + t * 256 + tid;
            const bool pred = (y[i] == cls);
            const u64 m = __ballot(pred);
            int wbase = 0;
            if (lane == 0 && m) wbase = atomicAdd(&cnt, (int)__popcll(m));
            wbase = __shfl(wbase, 0, 64);
            if (pred) {
                const int p = wbase + (int)__popcll(m & ((1ull << lane) - 1ull));
                if (p < CAPC) clist[lid * CAPC + p] = i;
            }
        }
        __syncthreads();
        if (tid == 0) ccnt[lid] = cnt < CAPC ? cnt : CAPC;
    }
}

// ---------------------------------------------------------------------------
// Kernel 2: bf16-MFMA GEMM (z @ M^T), LDS double-buffered, register ring of
// 4 k-slabs, single barrier per slab. Fused ||z||^2, distance epilogue,
// full contrastive loss, compact same-class distance write cd[N][8].
// Tile: 64 rows x 128 cols, BK=32, 512 blocks (2/CU), 256 threads.
// ---------------------------------------------------------------------------
#define BM 64
#define BN 128
#define BK 32
#define NS (HD / BK)   // 32 k-slabs
#define SA 40          // padded LDS stride in bf16 elems (80B)

__global__ __launch_bounds__(256, 2) void gemm_fused(
    const float* __restrict__ z, const __bf16* __restrict__ mvbf,
    const float* __restrict__ mn, float* __restrict__ cd,
    const int* __restrict__ y, float* __restrict__ lossAcc) {
    __shared__ __bf16 As[2][BM * SA];
    __shared__ __bf16 Bs[2][BN * SA];
    __shared__ float  szn[BM];
    __shared__ int    ly[BM];
    __shared__ float  spm[2][BM];
    __shared__ float  sns[2][BM];

    const int tid  = threadIdx.x;
    const int row0 = blockIdx.x * BM;
    const int lane = tid & 63;
    const int wave = tid >> 6;
    const int wr   = wave >> 1;   // 0..1 : 32-row strip
    const int wc   = wave & 1;    // 0..1 : 64-col strip
    const int l15  = lane & 15;
    const int quad = lane >> 4;

    const int sq = tid & 7;       // A staging: float4 slot in 32-wide k slab
    const int sr = tid >> 3;      // A staging: row 0..31 (rows sr, sr+32)
    const int bq = tid & 3;       // B staging: 16B chunk in k-slab
    const int br = tid >> 2;      // B staging: row 0..63 (rows br, br+64)

    if (tid < BM) ly[tid] = y[row0 + tid];

    f32x4 acc[2][4];
#pragma unroll
    for (int i = 0; i < 2; ++i)
#pragma unroll
        for (int j = 0; j < 4; ++j) acc[i][j] = (f32x4){0.f, 0.f, 0.f, 0.f};

    float zsq0 = 0.f, zsq1 = 0.f;

    const float*  zb = z + (size_t)(row0 + sr) * HD + sq * 4;
    const __bf16* bb = mvbf + (size_t)br * HD + bq * 8;

    // ---- register ring: 4 slabs in flight ----
    float4 ra0[4], ra1[4];
    bf16x8 rb0[4], rb1[4];
#pragma unroll
    for (int s = 0; s < 4; ++s) {          // issue slabs 0..3
        ra0[s] = *(const float4*)(zb + s * BK);
        ra1[s] = *(const float4*)(zb + s * BK + 32 * HD);
        rb0[s] = *(const bf16x8*)(bb + s * BK);
        rb1[s] = *(const bf16x8*)(bb + s * BK + 64 * HD);
    }
    // stage slab 0 into buf0, then reuse slot 0 for slab 4
    *(bf16x4*)&As[0][sr * SA + sq * 4]        = cvt4(ra0[0]);
    *(bf16x4*)&As[0][(sr + 32) * SA + sq * 4] = cvt4(ra1[0]);
    *(bf16x8*)&Bs[0][br * SA + bq * 8]        = rb0[0];
    *(bf16x8*)&Bs[0][(br + 64) * SA + bq * 8] = rb1[0];
    zsq0 += dot4(ra0[0]); zsq1 += dot4(ra1[0]);
    ra0[0] = *(const float4*)(zb + 4 * BK);
    ra1[0] = *(const float4*)(zb + 4 * BK + 32 * HD);
    rb0[0] = *(const bf16x8*)(bb + 4 * BK);
    rb1[0] = *(const bf16x8*)(bb + 4 * BK + 64 * HD);
    __syncthreads();

    // main loop: iter kt consumes LDS slab kt, stages slab kt+1 (ring slot
    // (kt+1)%4), issues loads for slab kt+5 into the freed slot.
    for (int it = 0; it < NS / 4; ++it) {
#pragma unroll
        for (int u = 0; u < 4; ++u) {
            const int kt = it * 4 + u;
            const int rbuf = kt & 1;
            const int ko = quad * 8;   // A[m][k=quad*8+j], B[n][k=quad*8+j]
            // step1: fragment reads for slab kt
            bf16x8 af[2], bfr[4];
#pragma unroll
            for (int i = 0; i < 2; ++i)
                af[i] = *(const bf16x8*)&As[rbuf][(wr * 32 + i * 16 + l15) * SA + ko];
#pragma unroll
            for (int j = 0; j < 4; ++j)
                bfr[j] = *(const bf16x8*)&Bs[rbuf][(wc * 64 + j * 16 + l15) * SA + ko];
            // step2: stage slab kt+1 from ring, issue loads for slab kt+5
            if (kt + 1 < NS) {
                const int w = (kt + 1) & 1;
                const int s = (kt + 1) & 3;
                *(bf16x4*)&As[w][sr * SA + sq * 4]        = cvt4(ra0[s]);
                *(bf16x4*)&As[w][(sr + 32) * SA + sq * 4] = cvt4(ra1[s]);
                *(bf16x8*)&Bs[w][br * SA + bq * 8]        = rb0[s];
                *(bf16x8*)&Bs[w][(br + 64) * SA + bq * 8] = rb1[s];
                zsq0 += dot4(ra0[s]); zsq1 += dot4(ra1[s]);
                if (kt + 5 < NS) {
                    const float*  zn = zb + (kt + 5) * BK;
                    const __bf16* bn = bb + (kt + 5) * BK;
                    ra0[s] = *(const float4*)(zn);
                    ra1[s] = *(const float4*)(zn + 32 * HD);
                    rb0[s] = *(const bf16x8*)(bn);
                    rb1[s] = *(const bf16x8*)(bn + 64 * HD);
                }
            }
            // step3: MFMA on slab kt
#pragma unroll
            for (int i = 0; i < 2; ++i)
#pragma unroll
                for (int j = 0; j < 4; ++j)
                    acc[i][j] = __builtin_amdgcn_mfma_f32_16x16x32_bf16(
                        af[i], bfr[j], acc[i][j], 0, 0, 0);
            // step4: one barrier per slab
            __syncthreads();
        }
    }

    // reduce ||z||^2 across the 8 staging lanes sharing each row
#pragma unroll
    for (int o = 1; o < 8; o <<= 1) {
        zsq0 += __shfl_xor(zsq0, o, 64);
        zsq1 += __shfl_xor(zsq1, o, 64);
    }
    if (sq == 0) { szn[sr] = zsq0; szn[sr + 32] = zsq1; }
    __syncthreads();

    // epilogue: dist = ||z||^2 + ||m||^2 - 2*xp
    // C/D layout: col = lane&15, row = quad*4 + reg  [verified]
    f32x4 znv[2];
    int rcls[2][4];
#pragma unroll
    for (int i = 0; i < 2; ++i) {
        znv[i] = *(const f32x4*)&szn[wr * 32 + i * 16 + quad * 4];
#pragma unroll
        for (int reg = 0; reg < 4; ++reg)
            rcls[i][reg] = ly[wr * 32 + i * 16 + quad * 4 + reg];
    }
    float pm[2][4], ns[2][4];
#pragma unroll
    for (int i = 0; i < 2; ++i)
#pragma unroll
        for (int reg = 0; reg < 4; ++reg) { pm[i][reg] = 0.f; ns[i][reg] = 0.f; }

#pragma unroll
    for (int j = 0; j < 4; ++j) {
        const int c = wc * 64 + j * 16 + l15;
        const float mc = mn[c];
        const int ccls = c >> 3;
#pragma unroll
        for (int i = 0; i < 2; ++i) {
#pragma unroll
            for (int reg = 0; reg < 4; ++reg) {
                const int row = wr * 32 + i * 16 + quad * 4 + reg;
                float d = znv[i][reg] + mc - 2.f * acc[i][j][reg];
                float r = (d + 1.0f) * __builtin_amdgcn_rcpf(d + EPSV);
                float r2 = r * r;
                float s = r2 * r2 * r;   // ratio^5 == exp(log(ratio)/0.2)
                if (ccls == rcls[i][reg]) {
                    pm[i][reg] = fmaxf(pm[i][reg], s);
                    cd[(size_t)(row0 + row) * 8 + (c & 7)] = d;
                } else {
                    ns[i][reg] += s;
                }
            }
        }
    }
    // reduce across the 16 lanes (l15) of each quad group
#pragma unroll
    for (int o = 1; o < 16; o <<= 1) {
#pragma unroll
        for (int i = 0; i < 2; ++i)
#pragma unroll
            for (int reg = 0; reg < 4; ++reg) {
                pm[i][reg] = fmaxf(pm[i][reg], __shfl_xor(pm[i][reg], o, 64));
                ns[i][reg] += __shfl_xor(ns[i][reg], o, 64);
            }
    }
    if (l15 == 0) {
#pragma unroll
        for (int i = 0; i < 2; ++i)
#pragma unroll
            for (int reg = 0; reg < 4; ++reg) {
                const int row = wr * 32 + i * 16 + quad * 4 + reg;
                spm[wc][row] = pm[i][reg];
                sns[wc][row] = ns[i][reg];
            }
    }
    __syncthreads();
    if (tid < BM) {   // wave 0 only (BM=64)
        float p = fmaxf(spm[0][tid], spm[1][tid]);
        float nsum = sns[0][tid] + sns[1][tid];
        float li = logf((nsum + p) / p);   // = -log(pos/(neg+pos))
#pragma unroll
        for (int o = 1; o < 64; o <<= 1) li += __shfl_xor(li, o, 64);
        if (tid == 0) atomicAdd(lossAcc, li);
    }
}

// ---------------------------------------------------------------------------
// Kernel 3: stage-1 top-32. One block per (motif, 2048-row chunk) = 2048
// blocks. Reads the precomputed candidate list (<=256, coalesced), gathers
// cd, packs keys, bitonic-256 sorts (== value desc, idx asc), emits top-32.
// ---------------------------------------------------------------------------
__global__ __launch_bounds__(256) void sel1_k(const int* __restrict__ clist,
                                              const int* __restrict__ ccnt,
                                              const float* __restrict__ cd,
                                              u64* __restrict__ s1k) {
    __shared__ u64 keys[256];

    const int bid = blockIdx.x;
    const int j = bid >> 4, chunk = bid & 15;
    const int cls = j >> 3, m8 = j & 7;
    const int lid = cls * 16 + chunk;
    const int tid = threadIdx.x;

    const int n = ccnt[lid];
    u64 key = ~0ull;
    if (tid < n) {
        const int idx = clist[lid * CAPC + tid];
        key = pack_key(cd[(size_t)idx * 8 + m8], idx);
    }
    keys[tid] = key;
    __syncthreads();

    // bitonic sort, 256 elems, threads 0..127 act (1 pair each), ascending
    for (int k = 2; k <= 256; k <<= 1) {
        for (int jj = k >> 1; jj > 0; jj >>= 1) {
            if (tid < 128) {
                const int i  = ((tid & ~(jj - 1)) << 1) | (tid & (jj - 1));
                const int ix = i | jj;
                const u64 A = keys[i], B = keys[ix];
                const bool up = ((i & k) == 0);
                if ((A > B) == up) { keys[i] = B; keys[ix] = A; }
            }
            __syncthreads();
        }
    }
    if (tid < KSEL) s1k[(size_t)j * 512 + chunk * KSEL + tid] = keys[tid];
}

// ---------------------------------------------------------------------------
// Kernel 4: merge 16x32 stage-1 keys -> global top-32 (bitonic-512, redundant
// per column-quarter), gather-mean of selected z rows, tau-blend, write.
// 512 blocks: (motif j = b>>2, column quarter q = b&3).
// ---------------------------------------------------------------------------
__global__ __launch_bounds__(256) void merge_k(
    const float* __restrict__ z, const float* __restrict__ mv,
    const u64* __restrict__ s1k, const float* __restrict__ lossAcc,
    float* __restrict__ out) {
    __shared__ u64 keys[512];
    __shared__ int sel[KSEL];

    const int b = blockIdx.x;
    const int j = b >> 2, q = b & 3;
    const int tid = threadIdx.x;
    keys[tid]       = s1k[(size_t)j * 512 + tid];
    keys[tid + 256] = s1k[(size_t)j * 512 + 256 + tid];
    __syncthreads();

    // bitonic sort, 512 elems, 256 threads = 1 pair each, ascending
    for (int k = 2; k <= 512; k <<= 1) {
        for (int jj = k >> 1; jj > 0; jj >>= 1) {
            const int i  = ((tid & ~(jj - 1)) << 1) | (tid & (jj - 1));
            const int ix = i | jj;
            const u64 A = keys[i], B = keys[ix];
            const bool up = ((i & k) == 0);
            if ((A > B) == up) { keys[i] = B; keys[ix] = A; }
            __syncthreads();
        }
    }
    if (tid < KSEL) sel[tid] = (int)(keys[tid] & 0xFFFFFFFFu);
    __syncthreads();

    const int h = q * 256 + tid;
    float s = 0.f;
#pragma unroll 8
    for (int r = 0; r < KSEL; ++r) s += z[(size_t)sel[r] * HD + h];
    out[1 + (size_t)j * HD + h] =
        0.99f * mv[(size_t)j * HD + h] + 0.01f * (s * (1.0f / KSEL));
    if (b == 0 && tid == 0) out[0] = lossAcc[0] * (1.0f / NROWS);
}

// ---------------------------------------------------------------------------
extern "C" void kernel_launch(void* const* d_in, const int* in_sizes, int n_in,
                              void* d_out, int out_size, void* d_ws, size_t ws_size,
                              hipStream_t stream) {
    const float* z  = (const float*)d_in[0];
    const float* mv = (const float*)d_in[1];
    const int*   y  = (const int*)d_in[2];
    float* out = (float*)d_out;
    float* wsf = (float*)d_ws;
    float*  mn    = wsf + WS_MN;
    __bf16* mvbf  = (__bf16*)(wsf + WS_MVBF);
    float*  cd    = wsf + WS_CD;
    u64*    s1k   = (u64*)(wsf + WS_S1K);
    int*    clist = (int*)(wsf + WS_CL);
    int*    ccnt  = (int*)(wsf + WS_CCNT);

    hipLaunchKernelGGL(prep_k,     dim3(NMOT + 256), dim3(256), 0, stream,
                       mv, y, wsf, mvbf, clist, ccnt);
    hipLaunchKernelGGL(gemm_fused, dim3(NROWS / BM), dim3(256), 0, stream,
                       z, mvbf, mn, cd, y, wsf);
    hipLaunchKernelGGL(sel1_k,     dim3(NMOT * 16),  dim3(256), 0, stream,
                       clist, ccnt, cd, s1k);
    hipLaunchKernelGGL(merge_k,    dim3(NMOT * 4),   dim3(256), 0, stream,
                       z, mv, s1k, wsf, out);
}